// Round 20
// baseline (31.163 us; speedup 1.0000x reference)
//
#include <hip/hip_runtime.h>

// Chamfer distance, B=4, N=8192, fp32 3-D points, MI355X.
// Round 20: r18 main (byte-identical; best verified 27.1us) + FUSED
// reduce+final (one 4-block x 1024-thr kernel replaces reduce(256 blk) +
// final(4 blk)): one fewer launch + gap + partial round-trip. r19's pins
// were null -> reverted. Fixed-cost model: ~7-9us of the 27.1 was
// launches/gaps/reduce/final; this removes ~a third of that.
// K-slot packing (verified r3-r19):
//   A g0={hx,hy,hz,hx,hy,hz,lx,ly}  g1={lz,sh,sl,1,1,0,0,0}
//   B g0={-2hx,-2hy,-2hz,-2lx,-2ly,-2lz,-2hx,-2hy}  g1={-2hz,1,1,sh,sl,0,0,0}

typedef _Float16 half8  __attribute__((ext_vector_type(8)));
typedef float    f32x16 __attribute__((ext_vector_type(16)));

#define NPTS   8192
#define NB     4
#define SPLITS 8
#define TPW    32                  // B-tiles per window
#define QWIN   (TPW * 32)          // 1024 q-points per window

#define MFMA_Z(d, a, b)                                                \
    asm("v_mfma_f32_32x32x16_f16 %0, %1, %2, 0"                        \
        : "=&v"(d) : "v"(a), "v"(b))

#define MIN3(dst, s0, s1)                                              \
    asm("v_min3_f32 %0, %1, %2, %0"                                    \
        : "+v"(dst) : "v"(s0), "v"(s1))

#define SB() __builtin_amdgcn_sched_barrier(0)

// rotation body: one B-pair vs both A-frags, zero nops
#define PAIR_ROT(q0, q1)                                               \
    do {                                                               \
        MFMA_Z(x0, a0, q0);                                            \
        MFMA_Z(x1, a0, q1);                                            \
        SB();                                                          \
        _Pragma("unroll")                                              \
        for (int r = 0; r < 16; ++r) MIN3(rm1[r], y0[r], y1[r]);       \
        SB();                                                          \
        MFMA_Z(y0, a1, q0);                                            \
        MFMA_Z(y1, a1, q1);                                            \
        SB();                                                          \
        _Pragma("unroll")                                              \
        for (int r = 0; r < 16; ++r) MIN3(rm0[r], x0[r], x1[r]);       \
        SB();                                                          \
    } while (0)

// ---------- main: 2048 blocks x 256 thr (4 waves) ----------
// block = (dir, b, qsplit-of-8, ptile-of-256); wave = 64 p-rows (2 A-tiles).
__global__ __launch_bounds__(256) void chamfer_main(
    const float* __restrict__ pc1, const float* __restrict__ pc2,
    float* __restrict__ ws_row)
{
    // Bf: fragment window (34 KiB); reused after the loop as the 32 KiB
    // block-reduction buffer.
    __shared__ half8 Bf[(TPW + 2) * 64];

    int bid = blockIdx.x;
    const int pt  = bid & 31;            bid >>= 5;
    const int qs  = bid & (SPLITS - 1);  bid >>= 3;
    const int b   = bid & (NB - 1);      bid >>= 2;
    const int dir = bid;

    const int tid = threadIdx.x;
    const int w = tid >> 6, lane = tid & 63;
    const int col = lane & 31, g = lane >> 5;
    const int pbase = pt * 256 + w * 64;       // this wave: rows pbase..pbase+63

    const float* Acl = dir ? pc2 : pc1;        // row side
    const float* Bcl = dir ? pc1 : pc2;        // col side

    const _Float16 one = (_Float16)1.0f, zz = (_Float16)0.0f;

    // ---- build this block's B-fragment window in LDS (4 points/thread) ----
    for (int i = tid; i < QWIN; i += 256) {
        const int t = i >> 5, c = i & 31;
        const float* Q = Bcl + ((size_t)b * NPTS + qs * QWIN + i) * 3;
        const float qx = Q[0], qy = Q[1], qz = Q[2];

        const _Float16 hx = (_Float16)qx, hy = (_Float16)qy, hz = (_Float16)qz;
        const _Float16 lx = (_Float16)(qx - (float)hx);
        const _Float16 ly = (_Float16)(qy - (float)hy);
        const _Float16 lz = (_Float16)(qz - (float)hz);
        const float sq = fmaf(qx, qx, fmaf(qy, qy, qz * qz));
        const _Float16 sh = (_Float16)sq;
        const _Float16 sl = (_Float16)(sq - (float)sh);

        const _Float16 nhx = (_Float16)(-2.0f * (float)hx);
        const _Float16 nhy = (_Float16)(-2.0f * (float)hy);
        const _Float16 nhz = (_Float16)(-2.0f * (float)hz);
        const _Float16 nlx = (_Float16)(-2.0f * (float)lx);
        const _Float16 nly = (_Float16)(-2.0f * (float)ly);
        const _Float16 nlz = (_Float16)(-2.0f * (float)lz);

        Bf[t * 64 + c]      = (half8){nhx, nhy, nhz, nlx, nly, nlz, nhx, nhy};
        Bf[t * 64 + 32 + c] = (half8){nhz, one, one, sh,  sl,  zz,  zz,  zz};
    }

    // ---- TWO A fragments (rows pbase+col, pbase+32+col) ----
    half8 a0, a1;
    #pragma unroll
    for (int h = 0; h < 2; ++h) {
        const float* P = Acl + ((size_t)b * NPTS + pbase + h * 32 + col) * 3;
        const float px = P[0], py = P[1], pz = P[2];
        const _Float16 hx = (_Float16)px, hy = (_Float16)py, hz = (_Float16)pz;
        const _Float16 lx = (_Float16)(px - (float)hx);
        const _Float16 ly = (_Float16)(py - (float)hy);
        const _Float16 lz = (_Float16)(pz - (float)hz);
        const float sq1 = fmaf(px, px, fmaf(py, py, pz * pz));
        const _Float16 sh = (_Float16)sq1;
        const _Float16 sl = (_Float16)(sq1 - (float)sh);
        half8 a;
        if (g == 0) a = (half8){hx, hy, hz, hx, hy, hz, lx, ly};
        else        a = (half8){lz, sh, sl, one, one, zz, zz, zz};
        if (h == 0) a0 = a; else a1 = a;
    }

    float rm0[16], rm1[16];
    #pragma unroll
    for (int r = 0; r < 16; ++r) { rm0[r] = 3.402823466e+38f;
                                   rm1[r] = 3.402823466e+38f; }

    __syncthreads();   // LDS build complete; read-only until the next barrier

    half8 pA0 = Bf[0 * 64 + lane], pA1 = Bf[1 * 64 + lane];
    half8 pB0 = Bf[2 * 64 + lane], pB1 = Bf[3 * 64 + lane];
    f32x16 x0, x1, y0, y1;

    // ---- peeled pair 0 (tiles 0,1): no y_prev yet -> one nop wall ----
    MFMA_Z(x0, a0, pA0);
    MFMA_Z(x1, a0, pA1);
    SB();
    asm volatile("s_nop 7\n\ts_nop 7\n\ts_nop 3");
    SB();
    MFMA_Z(y0, a1, pA0);
    MFMA_Z(y1, a1, pA1);
    SB();
    #pragma unroll
    for (int r = 0; r < 16; ++r) MIN3(rm0[r], x0[r], x1[r]);
    SB();
    pA0 = Bf[4 * 64 + lane];
    pA1 = Bf[5 * 64 + lane];

    // ---- pairs 1..14 (7 iters x 2 pairs), zero nops ----
    for (int j = 0; j < 7; ++j) {
        PAIR_ROT(pB0, pB1);
        pB0 = Bf[(6 + 4 * j) * 64 + lane];
        pB1 = Bf[(7 + 4 * j) * 64 + lane];
        PAIR_ROT(pA0, pA1);
        pA0 = Bf[(8 + 4 * j) * 64 + lane];   // j=6 -> tiles 32,33 (pad, unused)
        pA1 = Bf[(9 + 4 * j) * 64 + lane];
    }

    // ---- final pair 15 (tiles 30,31) + epilogue fold of the last y ----
    PAIR_ROT(pB0, pB1);
    #pragma unroll
    for (int r = 0; r < 16; ++r) MIN3(rm1[r], y0[r], y1[r]);

    // ---- epilogue: LDS block-reduce + coalesced store (r17 pattern) ----
    __syncthreads();                       // all waves done reading Bf
    float* RB = (float*)Bf;                // 4 waves x 2 h x 16 r x 64 lanes
    #pragma unroll
    for (int r = 0; r < 16; ++r) {
        RB[((w * 2 + 0) * 16 + r) * 64 + lane] = rm0[r];
        RB[((w * 2 + 1) * 16 + r) * 64 + lane] = rm1[r];
    }
    __syncthreads();

    {
        const int ww = tid >> 6, h = (tid >> 5) & 1, R = tid & 31;
        const int r  = (R & 3) + 4 * (R >> 3);
        const int gg = (R >> 2) & 1;
        const float* src = RB + (((ww * 2 + h) * 16 + r) * 64 + gg * 32);
        float m0 = fminf(src[0], src[1]);
        #pragma unroll
        for (int k = 2; k < 32; k += 2)
            m0 = fminf(m0, fminf(src[k], src[k + 1]));
        const size_t obase = (((size_t)dir * NB + b) * SPLITS + qs) * NPTS
                             + (size_t)pt * 256;
        ws_row[obase + ww * 64 + h * 32 + R] = m0;
    }
}

// ---------- finish (FUSED reduce+final): 4 blocks x 1024 thr ----------
// block = batch b; thread folds 8 splits for its p-rows in both dirs,
// accumulates, then 16-wave block sum -> out[b].
__global__ __launch_bounds__(1024) void chamfer_finish(
    const float* __restrict__ ws_row, float* __restrict__ out)
{
    const int b   = blockIdx.x;
    const int tid = threadIdx.x;

    float sum = 0.0f;
    #pragma unroll
    for (int dir = 0; dir < 2; ++dir) {
        const float* base = ws_row + (((size_t)dir * NB + b) * SPLITS) * NPTS;
        #pragma unroll
        for (int k = 0; k < NPTS / 1024; ++k) {
            const int p = k * 1024 + tid;
            float m0 = fminf(base[p],            base[NPTS + p]);
            float m1 = fminf(base[2 * NPTS + p], base[3 * NPTS + p]);
            float m2 = fminf(base[4 * NPTS + p], base[5 * NPTS + p]);
            float m3 = fminf(base[6 * NPTS + p], base[7 * NPTS + p]);
            sum += fminf(fminf(m0, m1), fminf(m2, m3));
        }
    }

    for (int off = 32; off; off >>= 1) sum += __shfl_down(sum, off, 64);

    __shared__ float red[16];
    if (!(tid & 63)) red[tid >> 6] = sum;
    __syncthreads();
    if (tid < 64) {
        float v = (tid < 16) ? red[tid] : 0.0f;
        for (int off = 8; off; off >>= 1) v += __shfl_down(v, off, 64);
        if (!tid) out[b] = v * (1.0f / (float)NPTS);
    }
}

extern "C" void kernel_launch(void* const* d_in, const int* in_sizes, int n_in,
                              void* d_out, int out_size, void* d_ws, size_t ws_size,
                              hipStream_t stream)
{
    const float* pc1 = (const float*)d_in[0];
    const float* pc2 = (const float*)d_in[1];
    float* out = (float*)d_out;

    float* ws_row = (float*)d_ws;               // 2*4*8*8192*4B = 2 MiB

    chamfer_main<<<2048, 256, 0, stream>>>(pc1, pc2, ws_row);
    chamfer_finish<<<NB, 1024, 0, stream>>>(ws_row, out);
}

// Round 21
// 28.191 us; speedup vs baseline: 1.1054x; 1.1054x over previous
//
#include <hip/hip_runtime.h>

// Chamfer distance, B=4, N=8192, fp32 3-D points, MI355X.
// Round 21: r18 core + 4 A-frags/wave (DS-pipe lever) + r18 tail restored
// (r20's 4-block fused finish was latency-bound, -4us; launches are cheap).
// DS model: r18 inner loop = 262K ds_read_b128 ~ 5.1us serialized per-CU
// (85 B/cyc, m134) -- largest pipe; explains occupancy nulls (per-CU
// resource) and r17's win. 4 A-frags -> reads/MFMA 0.5 -> 0.25.
// Rotation still uses only x,y acc tuples (a0->fold rm3, a1->fold rm0,
// a2->fold rm1, a3->fold rm2); every MFMA->read distance >= 48 cyc.
// Epilogue: two passes of the r17 LDS block-reduce (RB <= 32KB reuse of Bf).
// K-slot packing (verified r3-r20):
//   A g0={hx,hy,hz,hx,hy,hz,lx,ly}  g1={lz,sh,sl,1,1,0,0,0}
//   B g0={-2hx,-2hy,-2hz,-2lx,-2ly,-2lz,-2hx,-2hy}  g1={-2hz,1,1,sh,sl,0,0,0}

typedef _Float16 half8  __attribute__((ext_vector_type(8)));
typedef float    f32x16 __attribute__((ext_vector_type(16)));

#define NPTS   8192
#define NB     4
#define SPLITS 8
#define TPW    32                  // B-tiles per window
#define QWIN   (TPW * 32)          // 1024 q-points per window

#define MFMA_Z(d, a, b)                                                \
    asm("v_mfma_f32_32x32x16_f16 %0, %1, %2, 0"                        \
        : "=&v"(d) : "v"(a), "v"(b))

#define MIN3(dst, s0, s1)                                              \
    asm("v_min3_f32 %0, %1, %2, %0"                                    \
        : "+v"(dst) : "v"(s0), "v"(s1))

#define SB() __builtin_amdgcn_sched_barrier(0)

#define FOLD(rm, u0, u1)                                               \
    do { _Pragma("unroll")                                             \
         for (int r = 0; r < 16; ++r) MIN3(rm[r], u0[r], u1[r]); } while (0)

// 4-frag rotation: one B-pair vs a0..a3; y carries a3's accs across pairs
#define ROT4(q0, q1)                                                   \
    do {                                                               \
        MFMA_Z(x0, a0, q0); MFMA_Z(x1, a0, q1);                        \
        SB(); FOLD(rm3, y0, y1); SB();                                 \
        MFMA_Z(y0, a1, q0); MFMA_Z(y1, a1, q1);                        \
        SB(); FOLD(rm0, x0, x1); SB();                                 \
        MFMA_Z(x0, a2, q0); MFMA_Z(x1, a2, q1);                        \
        SB(); FOLD(rm1, y0, y1); SB();                                 \
        MFMA_Z(y0, a3, q0); MFMA_Z(y1, a3, q1);                        \
        SB(); FOLD(rm2, x0, x1); SB();                                 \
    } while (0)

// ---------- main: 1024 blocks x 256 thr (4 waves) ----------
// block = (dir, b, qsplit-of-8, ptile-of-512); wave = 128 p-rows (4 A-tiles).
__global__ __launch_bounds__(256) void chamfer_main(
    const float* __restrict__ pc1, const float* __restrict__ pc2,
    float* __restrict__ ws_row)
{
    // Bf: fragment window (34 KiB); reused after the loop as the 32 KiB
    // two-pass block-reduction buffer.
    __shared__ half8 Bf[(TPW + 2) * 64];

    int bid = blockIdx.x;
    const int pt  = bid & 15;            bid >>= 4;
    const int qs  = bid & (SPLITS - 1);  bid >>= 3;
    const int b   = bid & (NB - 1);      bid >>= 2;
    const int dir = bid;

    const int tid = threadIdx.x;
    const int w = tid >> 6, lane = tid & 63;
    const int col = lane & 31, g = lane >> 5;
    const int pbase = pt * 512 + w * 128;      // this wave: rows pbase..pbase+127

    const float* Acl = dir ? pc2 : pc1;        // row side
    const float* Bcl = dir ? pc1 : pc2;        // col side

    const _Float16 one = (_Float16)1.0f, zz = (_Float16)0.0f;

    // ---- build this block's B-fragment window in LDS (4 points/thread) ----
    for (int i = tid; i < QWIN; i += 256) {
        const int t = i >> 5, c = i & 31;
        const float* Q = Bcl + ((size_t)b * NPTS + qs * QWIN + i) * 3;
        const float qx = Q[0], qy = Q[1], qz = Q[2];

        const _Float16 hx = (_Float16)qx, hy = (_Float16)qy, hz = (_Float16)qz;
        const _Float16 lx = (_Float16)(qx - (float)hx);
        const _Float16 ly = (_Float16)(qy - (float)hy);
        const _Float16 lz = (_Float16)(qz - (float)hz);
        const float sq = fmaf(qx, qx, fmaf(qy, qy, qz * qz));
        const _Float16 sh = (_Float16)sq;
        const _Float16 sl = (_Float16)(sq - (float)sh);

        const _Float16 nhx = (_Float16)(-2.0f * (float)hx);
        const _Float16 nhy = (_Float16)(-2.0f * (float)hy);
        const _Float16 nhz = (_Float16)(-2.0f * (float)hz);
        const _Float16 nlx = (_Float16)(-2.0f * (float)lx);
        const _Float16 nly = (_Float16)(-2.0f * (float)ly);
        const _Float16 nlz = (_Float16)(-2.0f * (float)lz);

        Bf[t * 64 + c]      = (half8){nhx, nhy, nhz, nlx, nly, nlz, nhx, nhy};
        Bf[t * 64 + 32 + c] = (half8){nhz, one, one, sh,  sl,  zz,  zz,  zz};
    }

    // ---- FOUR A fragments (rows pbase + h*32 + col) ----
    half8 a0, a1, a2, a3;
    #pragma unroll
    for (int h = 0; h < 4; ++h) {
        const float* P = Acl + ((size_t)b * NPTS + pbase + h * 32 + col) * 3;
        const float px = P[0], py = P[1], pz = P[2];
        const _Float16 hx = (_Float16)px, hy = (_Float16)py, hz = (_Float16)pz;
        const _Float16 lx = (_Float16)(px - (float)hx);
        const _Float16 ly = (_Float16)(py - (float)hy);
        const _Float16 lz = (_Float16)(pz - (float)hz);
        const float sq1 = fmaf(px, px, fmaf(py, py, pz * pz));
        const _Float16 sh = (_Float16)sq1;
        const _Float16 sl = (_Float16)(sq1 - (float)sh);
        half8 a;
        if (g == 0) a = (half8){hx, hy, hz, hx, hy, hz, lx, ly};
        else        a = (half8){lz, sh, sl, one, one, zz, zz, zz};
        if      (h == 0) a0 = a;
        else if (h == 1) a1 = a;
        else if (h == 2) a2 = a;
        else             a3 = a;
    }

    float rm0[16], rm1[16], rm2[16], rm3[16];
    #pragma unroll
    for (int r = 0; r < 16; ++r) {
        rm0[r] = 3.402823466e+38f; rm1[r] = 3.402823466e+38f;
        rm2[r] = 3.402823466e+38f; rm3[r] = 3.402823466e+38f;
    }

    __syncthreads();   // LDS build complete; read-only until the next barrier

    half8 pA0 = Bf[0 * 64 + lane], pA1 = Bf[1 * 64 + lane];
    half8 pB0 = Bf[2 * 64 + lane], pB1 = Bf[3 * 64 + lane];
    f32x16 x0, x1, y0, y1;

    // ---- peeled pair 0: no y_prev -> one nop wall, fold rm0..rm2 ----
    MFMA_Z(x0, a0, pA0); MFMA_Z(x1, a0, pA1);
    SB();
    asm volatile("s_nop 7\n\ts_nop 7\n\ts_nop 3");
    SB();
    MFMA_Z(y0, a1, pA0); MFMA_Z(y1, a1, pA1);
    SB(); FOLD(rm0, x0, x1); SB();
    MFMA_Z(x0, a2, pA0); MFMA_Z(x1, a2, pA1);
    SB(); FOLD(rm1, y0, y1); SB();
    MFMA_Z(y0, a3, pA0); MFMA_Z(y1, a3, pA1);
    SB(); FOLD(rm2, x0, x1); SB();
    pA0 = Bf[4 * 64 + lane];
    pA1 = Bf[5 * 64 + lane];

    // ---- pairs 1..14 (7 iters x 2 pairs), zero nops ----
    for (int j = 0; j < 7; ++j) {
        ROT4(pB0, pB1);
        pB0 = Bf[(6 + 4 * j) * 64 + lane];
        pB1 = Bf[(7 + 4 * j) * 64 + lane];
        ROT4(pA0, pA1);
        pA0 = Bf[(8 + 4 * j) * 64 + lane];   // j=6 -> pad tiles 32,33 (unused)
        pA1 = Bf[(9 + 4 * j) * 64 + lane];
    }

    // ---- final pair 15 + epilogue fold of the last y (a3) ----
    ROT4(pB0, pB1);
    FOLD(rm3, y0, y1);

    // ---- epilogue: TWO passes of the r17 LDS block-reduce ----
    const size_t obase = (((size_t)dir * NB + b) * SPLITS + qs) * NPTS
                         + (size_t)pt * 512;
    float* RB = (float*)Bf;                // 4 waves x 2 frags x 16 r x 64 lanes

    // pass 1: frags 0,1 (rows pbase + 0..63)
    __syncthreads();
    #pragma unroll
    for (int r = 0; r < 16; ++r) {
        RB[((w * 2 + 0) * 16 + r) * 64 + lane] = rm0[r];
        RB[((w * 2 + 1) * 16 + r) * 64 + lane] = rm1[r];
    }
    __syncthreads();
    {
        const int ww = tid >> 6, h = (tid >> 5) & 1, R = tid & 31;
        const int r  = (R & 3) + 4 * (R >> 3);
        const int gg = (R >> 2) & 1;
        const float* src = RB + (((ww * 2 + h) * 16 + r) * 64 + gg * 32);
        float m0 = fminf(src[0], src[1]);
        #pragma unroll
        for (int k = 2; k < 32; k += 2)
            m0 = fminf(m0, fminf(src[k], src[k + 1]));
        ws_row[obase + ww * 128 + h * 32 + R] = m0;
    }

    // pass 2: frags 2,3 (rows pbase + 64..127)
    __syncthreads();
    #pragma unroll
    for (int r = 0; r < 16; ++r) {
        RB[((w * 2 + 0) * 16 + r) * 64 + lane] = rm2[r];
        RB[((w * 2 + 1) * 16 + r) * 64 + lane] = rm3[r];
    }
    __syncthreads();
    {
        const int ww = tid >> 6, h = (tid >> 5) & 1, R = tid & 31;
        const int r  = (R & 3) + 4 * (R >> 3);
        const int gg = (R >> 2) & 1;
        const float* src = RB + (((ww * 2 + h) * 16 + r) * 64 + gg * 32);
        float m0 = fminf(src[0], src[1]);
        #pragma unroll
        for (int k = 2; k < 32; k += 2)
            m0 = fminf(m0, fminf(src[k], src[k + 1]));
        ws_row[obase + ww * 128 + 64 + h * 32 + R] = m0;
    }
}

// ---------- reduce: 256 blocks; min over 8 splits, block partial sums ----------
__global__ __launch_bounds__(256) void chamfer_reduce(
    const float* __restrict__ ws_row, float* __restrict__ partial)
{
    int bid = blockIdx.x;                    // 2 dir x 4 b x 32 slices
    const int sl  = bid & 31; bid >>= 5;
    const int b   = bid & 3;  bid >>= 2;
    const int dir = bid;

    const int p = sl * 256 + threadIdx.x;
    const float* base = ws_row + (((size_t)dir * NB + b) * SPLITS) * NPTS + p;
    float m0 = fminf(base[0],        base[NPTS]);
    float m1 = fminf(base[2 * NPTS], base[3 * NPTS]);
    float m2 = fminf(base[4 * NPTS], base[5 * NPTS]);
    float m3 = fminf(base[6 * NPTS], base[7 * NPTS]);
    float sum = fminf(fminf(m0, m1), fminf(m2, m3));

    for (int off = 32; off; off >>= 1) sum += __shfl_down(sum, off, 64);
    __shared__ float red[4];
    if (!(threadIdx.x & 63)) red[threadIdx.x >> 6] = sum;
    __syncthreads();
    if (!threadIdx.x)
        partial[blockIdx.x] = red[0] + red[1] + red[2] + red[3];
}

// ---------- final: 4 blocks x 64 thr; each b sums its 64 partials ----------
__global__ __launch_bounds__(64) void chamfer_final(
    const float* __restrict__ partial, float* __restrict__ out)
{
    const int b = blockIdx.x, t = threadIdx.x;
    const int dir = t >> 5, sl = t & 31;
    float v = partial[(((size_t)dir * NB + b) << 5) + sl];
    for (int off = 32; off; off >>= 1) v += __shfl_down(v, off, 64);
    if (!t) out[b] = v * (1.0f / (float)NPTS);
}

extern "C" void kernel_launch(void* const* d_in, const int* in_sizes, int n_in,
                              void* d_out, int out_size, void* d_ws, size_t ws_size,
                              hipStream_t stream)
{
    const float* pc1 = (const float*)d_in[0];
    const float* pc2 = (const float*)d_in[1];
    float* out = (float*)d_out;

    char* ws = (char*)d_ws;
    float* ws_row  = (float*)ws;                // 2*4*8*8192*4B = 2 MiB
    float* partial = (float*)(ws + (2 << 20));  // 1 KiB

    chamfer_main<<<1024, 256, 0, stream>>>(pc1, pc2, ws_row);
    chamfer_reduce<<<256, 256, 0, stream>>>(ws_row, partial);
    chamfer_final<<<NB, 64, 0, stream>>>(partial, out);
}

// Round 22
// 26.953 us; speedup vs baseline: 1.1562x; 1.0460x over previous
//
#include <hip/hip_runtime.h>

// Chamfer distance, B=4, N=8192, fp32 3-D points, MI355X.
// FINAL (= round-18 config verbatim, best verified at 27.1us; r19 pins null,
// r20 fused-tail regression, r21 4-A-frag null -> all reverted).
// Structure: MFMA K-slot algorithm on f16 hi/lo splits; LDS-resident
// B-fragment window; zero-nop software-pipelined min-fold rotation;
// LDS block-reduce epilogue with coalesced stores; 3-kernel pipeline.
// K-slot packing (verified r3-r21):
//   A g0={hx,hy,hz,hx,hy,hz,lx,ly}  g1={lz,sh,sl,1,1,0,0,0}
//   B g0={-2hx,-2hy,-2hz,-2lx,-2ly,-2lz,-2hx,-2hy}  g1={-2hz,1,1,sh,sl,0,0,0}
//   => acc = sq1 + sq2 - 2 p.q  (l.l' term ~2e-5 dropped, << 9.5e-4 thr)

typedef _Float16 half8  __attribute__((ext_vector_type(8)));
typedef float    f32x16 __attribute__((ext_vector_type(16)));

#define NPTS   8192
#define NB     4
#define SPLITS 8
#define TPW    32                  // B-tiles per window
#define QWIN   (TPW * 32)          // 1024 q-points per window

#define MFMA_Z(d, a, b)                                                \
    asm("v_mfma_f32_32x32x16_f16 %0, %1, %2, 0"                        \
        : "=&v"(d) : "v"(a), "v"(b))

#define MIN3(dst, s0, s1)                                              \
    asm("v_min3_f32 %0, %1, %2, %0"                                    \
        : "+v"(dst) : "v"(s0), "v"(s1))

#define SB() __builtin_amdgcn_sched_barrier(0)

// rotation body: one B-pair vs both A-frags, zero nops
#define PAIR_ROT(q0, q1)                                               \
    do {                                                               \
        MFMA_Z(x0, a0, q0);                                            \
        MFMA_Z(x1, a0, q1);                                            \
        SB();                                                          \
        _Pragma("unroll")                                              \
        for (int r = 0; r < 16; ++r) MIN3(rm1[r], y0[r], y1[r]);       \
        SB();                                                          \
        MFMA_Z(y0, a1, q0);                                            \
        MFMA_Z(y1, a1, q1);                                            \
        SB();                                                          \
        _Pragma("unroll")                                              \
        for (int r = 0; r < 16; ++r) MIN3(rm0[r], x0[r], x1[r]);       \
        SB();                                                          \
    } while (0)

// ---------- main: 2048 blocks x 256 thr (4 waves) ----------
// block = (dir, b, qsplit-of-8, ptile-of-256); wave = 64 p-rows (2 A-tiles).
__global__ __launch_bounds__(256) void chamfer_main(
    const float* __restrict__ pc1, const float* __restrict__ pc2,
    float* __restrict__ ws_row)
{
    // Bf: fragment window (34 KiB); reused after the loop as the 32 KiB
    // block-reduction buffer.
    __shared__ half8 Bf[(TPW + 2) * 64];

    int bid = blockIdx.x;
    const int pt  = bid & 31;            bid >>= 5;
    const int qs  = bid & (SPLITS - 1);  bid >>= 3;
    const int b   = bid & (NB - 1);      bid >>= 2;
    const int dir = bid;

    const int tid = threadIdx.x;
    const int w = tid >> 6, lane = tid & 63;
    const int col = lane & 31, g = lane >> 5;
    const int pbase = pt * 256 + w * 64;       // this wave: rows pbase..pbase+63

    const float* Acl = dir ? pc2 : pc1;        // row side
    const float* Bcl = dir ? pc1 : pc2;        // col side

    const _Float16 one = (_Float16)1.0f, zz = (_Float16)0.0f;

    // ---- build this block's B-fragment window in LDS (4 points/thread) ----
    for (int i = tid; i < QWIN; i += 256) {
        const int t = i >> 5, c = i & 31;
        const float* Q = Bcl + ((size_t)b * NPTS + qs * QWIN + i) * 3;
        const float qx = Q[0], qy = Q[1], qz = Q[2];

        const _Float16 hx = (_Float16)qx, hy = (_Float16)qy, hz = (_Float16)qz;
        const _Float16 lx = (_Float16)(qx - (float)hx);
        const _Float16 ly = (_Float16)(qy - (float)hy);
        const _Float16 lz = (_Float16)(qz - (float)hz);
        const float sq = fmaf(qx, qx, fmaf(qy, qy, qz * qz));
        const _Float16 sh = (_Float16)sq;
        const _Float16 sl = (_Float16)(sq - (float)sh);

        const _Float16 nhx = (_Float16)(-2.0f * (float)hx);
        const _Float16 nhy = (_Float16)(-2.0f * (float)hy);
        const _Float16 nhz = (_Float16)(-2.0f * (float)hz);
        const _Float16 nlx = (_Float16)(-2.0f * (float)lx);
        const _Float16 nly = (_Float16)(-2.0f * (float)ly);
        const _Float16 nlz = (_Float16)(-2.0f * (float)lz);

        Bf[t * 64 + c]      = (half8){nhx, nhy, nhz, nlx, nly, nlz, nhx, nhy};
        Bf[t * 64 + 32 + c] = (half8){nhz, one, one, sh,  sl,  zz,  zz,  zz};
    }

    // ---- TWO A fragments (rows pbase+col, pbase+32+col) ----
    half8 a0, a1;
    #pragma unroll
    for (int h = 0; h < 2; ++h) {
        const float* P = Acl + ((size_t)b * NPTS + pbase + h * 32 + col) * 3;
        const float px = P[0], py = P[1], pz = P[2];
        const _Float16 hx = (_Float16)px, hy = (_Float16)py, hz = (_Float16)pz;
        const _Float16 lx = (_Float16)(px - (float)hx);
        const _Float16 ly = (_Float16)(py - (float)hy);
        const _Float16 lz = (_Float16)(pz - (float)hz);
        const float sq1 = fmaf(px, px, fmaf(py, py, pz * pz));
        const _Float16 sh = (_Float16)sq1;
        const _Float16 sl = (_Float16)(sq1 - (float)sh);
        half8 a;
        if (g == 0) a = (half8){hx, hy, hz, hx, hy, hz, lx, ly};
        else        a = (half8){lz, sh, sl, one, one, zz, zz, zz};
        if (h == 0) a0 = a; else a1 = a;
    }

    float rm0[16], rm1[16];
    #pragma unroll
    for (int r = 0; r < 16; ++r) { rm0[r] = 3.402823466e+38f;
                                   rm1[r] = 3.402823466e+38f; }

    __syncthreads();   // LDS build complete; read-only until the next barrier

    half8 pA0 = Bf[0 * 64 + lane], pA1 = Bf[1 * 64 + lane];
    half8 pB0 = Bf[2 * 64 + lane], pB1 = Bf[3 * 64 + lane];
    f32x16 x0, x1, y0, y1;

    // ---- peeled pair 0 (tiles 0,1): no y_prev yet -> one nop wall ----
    MFMA_Z(x0, a0, pA0);
    MFMA_Z(x1, a0, pA1);
    SB();
    asm volatile("s_nop 7\n\ts_nop 7\n\ts_nop 3");
    SB();
    MFMA_Z(y0, a1, pA0);
    MFMA_Z(y1, a1, pA1);
    SB();
    #pragma unroll
    for (int r = 0; r < 16; ++r) MIN3(rm0[r], x0[r], x1[r]);
    SB();
    pA0 = Bf[4 * 64 + lane];
    pA1 = Bf[5 * 64 + lane];

    // ---- pairs 1..14 (7 iters x 2 pairs), zero nops ----
    for (int j = 0; j < 7; ++j) {
        PAIR_ROT(pB0, pB1);
        pB0 = Bf[(6 + 4 * j) * 64 + lane];
        pB1 = Bf[(7 + 4 * j) * 64 + lane];
        PAIR_ROT(pA0, pA1);
        pA0 = Bf[(8 + 4 * j) * 64 + lane];   // j=6 -> tiles 32,33 (pad, unused)
        pA1 = Bf[(9 + 4 * j) * 64 + lane];
    }

    // ---- final pair 15 (tiles 30,31) + epilogue fold of the last y ----
    PAIR_ROT(pB0, pB1);
    #pragma unroll
    for (int r = 0; r < 16; ++r) MIN3(rm1[r], y0[r], y1[r]);

    // ---- epilogue: LDS block-reduce + coalesced store (r17 pattern) ----
    __syncthreads();                       // all waves done reading Bf
    float* RB = (float*)Bf;                // 4 waves x 2 h x 16 r x 64 lanes
    #pragma unroll
    for (int r = 0; r < 16; ++r) {
        RB[((w * 2 + 0) * 16 + r) * 64 + lane] = rm0[r];
        RB[((w * 2 + 1) * 16 + r) * 64 + lane] = rm1[r];
    }
    __syncthreads();

    {
        const int ww = tid >> 6, h = (tid >> 5) & 1, R = tid & 31;
        const int r  = (R & 3) + 4 * (R >> 3);
        const int gg = (R >> 2) & 1;
        const float* src = RB + (((ww * 2 + h) * 16 + r) * 64 + gg * 32);
        float m0 = fminf(src[0], src[1]);
        #pragma unroll
        for (int k = 2; k < 32; k += 2)
            m0 = fminf(m0, fminf(src[k], src[k + 1]));
        const size_t obase = (((size_t)dir * NB + b) * SPLITS + qs) * NPTS
                             + (size_t)pt * 256;
        ws_row[obase + ww * 64 + h * 32 + R] = m0;
    }
}

// ---------- reduce: 256 blocks; min over 8 splits, block partial sums ----------
__global__ __launch_bounds__(256) void chamfer_reduce(
    const float* __restrict__ ws_row, float* __restrict__ partial)
{
    int bid = blockIdx.x;                    // 2 dir x 4 b x 32 slices
    const int sl  = bid & 31; bid >>= 5;
    const int b   = bid & 3;  bid >>= 2;
    const int dir = bid;

    const int p = sl * 256 + threadIdx.x;
    const float* base = ws_row + (((size_t)dir * NB + b) * SPLITS) * NPTS + p;
    float m0 = fminf(base[0],        base[NPTS]);
    float m1 = fminf(base[2 * NPTS], base[3 * NPTS]);
    float m2 = fminf(base[4 * NPTS], base[5 * NPTS]);
    float m3 = fminf(base[6 * NPTS], base[7 * NPTS]);
    float sum = fminf(fminf(m0, m1), fminf(m2, m3));

    for (int off = 32; off; off >>= 1) sum += __shfl_down(sum, off, 64);
    __shared__ float red[4];
    if (!(threadIdx.x & 63)) red[threadIdx.x >> 6] = sum;
    __syncthreads();
    if (!threadIdx.x)
        partial[blockIdx.x] = red[0] + red[1] + red[2] + red[3];
}

// ---------- final: 4 blocks x 64 thr; each b sums its 64 partials ----------
__global__ __launch_bounds__(64) void chamfer_final(
    const float* __restrict__ partial, float* __restrict__ out)
{
    const int b = blockIdx.x, t = threadIdx.x;
    const int dir = t >> 5, sl = t & 31;
    float v = partial[(((size_t)dir * NB + b) << 5) + sl];
    for (int off = 32; off; off >>= 1) v += __shfl_down(v, off, 64);
    if (!t) out[b] = v * (1.0f / (float)NPTS);
}

extern "C" void kernel_launch(void* const* d_in, const int* in_sizes, int n_in,
                              void* d_out, int out_size, void* d_ws, size_t ws_size,
                              hipStream_t stream)
{
    const float* pc1 = (const float*)d_in[0];
    const float* pc2 = (const float*)d_in[1];
    float* out = (float*)d_out;

    char* ws = (char*)d_ws;
    float* ws_row  = (float*)ws;                // 2*4*8*8192*4B = 2 MiB
    float* partial = (float*)(ws + (2 << 20));  // 1 KiB

    chamfer_main<<<2048, 256, 0, stream>>>(pc1, pc2, ws_row);
    chamfer_reduce<<<256, 256, 0, stream>>>(ws_row, partial);
    chamfer_final<<<NB, 64, 0, stream>>>(partial, out);
}